// Round 1
// baseline (98.445 us; speedup 1.0000x reference)
//
#include <hip/hip_runtime.h>

// SharedMultiCategoricalEncoder on MI355X.
// x: [B=8192, C=32, L=8] int32 ids in [0, 9311); emb: [9311, 64] fp32 (row 0 = zeros).
// out[b,c,:] = sum_l emb[x[b,c,l]] / max(#(x[b,c,l] > 0), 1)
//
// Thread mapping: 16 lanes per (b,c) pair, each lane owns a float4 chunk of the
// 64-wide channel dim. Row 0 of the table is zeros, so the padding mask is free
// on the sum (unconditional accumulate); only the count is conditional.

#define NPAIRS (8192 * 32)   // B*C = 262144
#define LL 8

__global__ __launch_bounds__(256) void
SharedMultiCategoricalEncoder_kernel(const int* __restrict__ x,
                                     const float4* __restrict__ emb4,
                                     float4* __restrict__ out4) {
    const int tid   = blockIdx.x * blockDim.x + threadIdx.x;   // one thread per (pair, chunk)
    const int pair  = tid >> 4;        // (b*C + c)
    const int chunk = tid & 15;        // which float4 of the 16 covering D=64

    // Load the 8 ids for this pair (32 B, 16-lane broadcast within the group; L1-served).
    const int4* xp = (const int4*)(x + pair * LL);
    const int4 id01 = xp[0];
    const int4 id23 = xp[1];
    const int ids[LL] = { id01.x, id01.y, id01.z, id01.w,
                          id23.x, id23.y, id23.z, id23.w };

    float4 acc = make_float4(0.f, 0.f, 0.f, 0.f);
    int cnt = 0;
#pragma unroll
    for (int l = 0; l < LL; ++l) {
        const int id = ids[l];                 // already in [0, 9311); row 0 is zeros
        const float4 e = emb4[id * 16 + chunk];
        acc.x += e.x; acc.y += e.y; acc.z += e.z; acc.w += e.w;
        cnt += (id > 0);
    }

    const float scale = 1.0f / (float)(cnt > 0 ? cnt : 1);
    acc.x *= scale; acc.y *= scale; acc.z *= scale; acc.w *= scale;
    out4[tid] = acc;                            // contiguous 1 KiB per wave
}

extern "C" void kernel_launch(void* const* d_in, const int* in_sizes, int n_in,
                              void* d_out, int out_size, void* d_ws, size_t ws_size,
                              hipStream_t stream) {
    const int*   x   = (const int*)d_in[0];
    const float* emb = (const float*)d_in[1];
    float*       out = (float*)d_out;

    // Total threads = NPAIRS * 16 = 4,194,304 -> 16384 blocks of 256.
    const int threads = 256;
    const int blocks  = (NPAIRS * 16) / threads;
    SharedMultiCategoricalEncoder_kernel<<<blocks, threads, 0, stream>>>(
        x, (const float4*)emb, (float4*)out);
}